// Round 2
// baseline (468.789 us; speedup 1.0000x reference)
//
#include <hip/hip_runtime.h>
#include <hip/hip_bf16.h>
#include <cstdint>

// ---------------------------------------------------------------------------
// MultiHeadAttention: B=4 S=2048 D=1024 H=16 DQ=DV=64
//   1) cast q/k/v fp32->bf16; transpose Wq/Wk/Wv/Wo to (N,K) bf16
//   2) GEMM (8192x1024x1024) x3 -> Qp, Kp (row-major bf16), Vt (per-head
//      transposed bf16  Vt[b][h][dv][s])
//   3) flash attention (swapped-QK mfma), scale = 1/sqrt(2048)
//   4) GEMM (8192x1024x1024) + bias -> fp32 out
// ---------------------------------------------------------------------------

typedef __attribute__((ext_vector_type(4))) float f32x4;
typedef __attribute__((ext_vector_type(8))) short bf16x8;

#define GLB const __attribute__((address_space(1))) void*
#define LDS __attribute__((address_space(3))) void*

__device__ __forceinline__ ushort f2bf(float f) {
    uint32_t u = __builtin_bit_cast(uint32_t, f);
    u += 0x7fffu + ((u >> 16) & 1u);   // round-to-nearest-even
    return (ushort)(u >> 16);
}

// ---------------- stage 1a: fp32 -> bf16 (vectorized) ----------------------
__global__ void convert_bf16(const float* __restrict__ in, ushort* __restrict__ out, int n4) {
    for (int i = blockIdx.x * blockDim.x + threadIdx.x; i < n4; i += gridDim.x * blockDim.x) {
        float4 v = reinterpret_cast<const float4*>(in)[i];
        ushort4 o;
        o.x = f2bf(v.x); o.y = f2bf(v.y); o.z = f2bf(v.z); o.w = f2bf(v.w);
        reinterpret_cast<ushort4*>(out)[i] = o;
    }
}

// ---------------- stage 1b: W (K=1024,N=1024) fp32 -> WT (N,K) bf16 --------
__global__ void transpose_w(const float* __restrict__ in, ushort* __restrict__ out) {
    __shared__ float tile[64][65];
    const int tx = threadIdx.x & 63, ty = threadIdx.x >> 6;
    const int nb = blockIdx.x * 64, kb = blockIdx.y * 64;
#pragma unroll
    for (int i = ty; i < 64; i += 4)
        tile[i][tx] = in[(size_t)(kb + i) * 1024 + nb + tx];
    __syncthreads();
#pragma unroll
    for (int i = ty; i < 64; i += 4)
        out[(size_t)(nb + i) * 1024 + kb + tx] = f2bf(tile[tx][i]);
}

// ---------------- stage 2/4: GEMM  C = A(M,K) * BT(N,K)^T + bias -----------
// MODE 0: bf16 row-major out.  MODE 1: V -> Vt[b][h][dv][s].  MODE 2: fp32 out.
template <int MODE>
__global__ __launch_bounds__(256) void gemm_bt(const ushort* __restrict__ A,
                                               const ushort* __restrict__ BT,
                                               const float* __restrict__ bias,
                                               ushort* __restrict__ Cb,
                                               float* __restrict__ Cf) {
    constexpr int K = 1024, N = 1024;
    __shared__ ushort As[128 * 32];
    __shared__ ushort Bs[128 * 32];
    const int tid = threadIdx.x;
    const int lane = tid & 63;
    const int wave = tid >> 6, wr = wave >> 1, wc = wave & 1;
    const int r = lane & 15, g = lane >> 4;
    const int mb = blockIdx.y * 128, nb = blockIdx.x * 128;

    f32x4 acc[4][4] = {};

    for (int k0 = 0; k0 < K; k0 += 32) {
#pragma unroll
        for (int j = 0; j < 2; ++j) {
            const int t = j * 256 + tid;
            const ushort* ga = A  + (size_t)(mb + (t >> 2)) * K + k0 + (t & 3) * 8;
            const ushort* gb = BT + (size_t)(nb + (t >> 2)) * K + k0 + (t & 3) * 8;
            const int lo = (j * 256 + (tid & ~63)) * 8;   // wave-uniform elem offset
            __builtin_amdgcn_global_load_lds((GLB)ga, (LDS)(As + lo), 16, 0, 0);
            __builtin_amdgcn_global_load_lds((GLB)gb, (LDS)(Bs + lo), 16, 0, 0);
        }
        __syncthreads();

        bf16x8 af[4], bfr[4];
#pragma unroll
        for (int i = 0; i < 4; ++i) {
            af[i]  = *(const bf16x8*)&As[(wr * 64 + i * 16 + r) * 32 + g * 8];
            bfr[i] = *(const bf16x8*)&Bs[(wc * 64 + i * 16 + r) * 32 + g * 8];
        }
#pragma unroll
        for (int mi = 0; mi < 4; ++mi)
#pragma unroll
            for (int ni = 0; ni < 4; ++ni)
                acc[mi][ni] = __builtin_amdgcn_mfma_f32_16x16x32_bf16(af[mi], bfr[ni], acc[mi][ni], 0, 0, 0);
        __syncthreads();
    }

#pragma unroll
    for (int ni = 0; ni < 4; ++ni) {
        const int col = nb + wc * 64 + ni * 16 + r;
        const float bv = bias[col];
#pragma unroll
        for (int mi = 0; mi < 4; ++mi) {
            const int m0 = mb + wr * 64 + mi * 16 + g * 4;
            if (MODE == 0) {
#pragma unroll
                for (int i = 0; i < 4; ++i)
                    Cb[(size_t)(m0 + i) * N + col] = f2bf(acc[mi][ni][i] + bv);
            } else if (MODE == 1) {
                const int b = m0 >> 11, s = m0 & 2047;
                const int h = col >> 6, dv = col & 63;
                ushort4 o;
                o.x = f2bf(acc[mi][ni][0] + bv);
                o.y = f2bf(acc[mi][ni][1] + bv);
                o.z = f2bf(acc[mi][ni][2] + bv);
                o.w = f2bf(acc[mi][ni][3] + bv);
                *(ushort4*)&Cb[(((size_t)(b * 16 + h) * 64 + dv) << 11) + s] = o;
            } else {
#pragma unroll
                for (int i = 0; i < 4; ++i)
                    Cf[(size_t)(m0 + i) * N + col] = acc[mi][ni][i] + bv;
            }
        }
    }
}

// ---------------- stage 3: flash attention ---------------------------------
// grid (qtile=16, h=16, b=4), block 256 (4 independent waves, 32 q-rows each)
// Qp,Kp: [b][s][h*64+dq] bf16 ; Vt: [b][h][dv][s] bf16 ; AO: [b][s][h*64+dv]
__global__ __launch_bounds__(256) void attn_kernel(const ushort* __restrict__ Qp,
                                                   const ushort* __restrict__ Kp,
                                                   const ushort* __restrict__ Vt,
                                                   ushort* __restrict__ AO) {
    const int lane = threadIdx.x & 63, wave = threadIdx.x >> 6;
    const int r = lane & 15, g = lane >> 4;
    const int qt = blockIdx.x, h = blockIdx.y, b = blockIdx.z;
    const int qbase = qt * 128 + wave * 32;
    const float scale = 0.022097086912079608f;   // 1/sqrt(2048)

    const ushort* Qh = Qp + (size_t)b * 2048 * 1024 + h * 64;
    const ushort* Kh = Kp + (size_t)b * 2048 * 1024 + h * 64;
    const ushort* Vh = Vt + ((size_t)(b * 16 + h)) * 64 * 2048;

    __shared__ ushort Plds[4][32 * 64];
    ushort* Pw = (ushort*)Plds[wave];

    // Q fragments (B-operand of swapped QK): qf[g2][kc]
    bf16x8 qf[2][2];
#pragma unroll
    for (int gg = 0; gg < 2; ++gg)
#pragma unroll
        for (int kc = 0; kc < 2; ++kc)
            qf[gg][kc] = *(const bf16x8*)&Qh[(size_t)(qbase + gg * 16 + r) * 1024 + kc * 32 + g * 8];

    f32x4 oacc[2][4] = {};
    float mrow[2] = {-3e30f, -3e30f};
    float ell[2] = {0.f, 0.f};

    for (int t0 = 0; t0 < 2048; t0 += 64) {
        // K fragments (A-operand): kf[tf][kc]
        bf16x8 kf[4][2];
#pragma unroll
        for (int tf = 0; tf < 4; ++tf)
#pragma unroll
            for (int kc = 0; kc < 2; ++kc)
                kf[tf][kc] = *(const bf16x8*)&Kh[(size_t)(t0 + tf * 16 + r) * 1024 + kc * 32 + g * 8];

        // St = K * Q^T : St[t][q],  t = 16*tf + 4*g + i,  q = 16*gg + r
        f32x4 st[2][4] = {};
#pragma unroll
        for (int gg = 0; gg < 2; ++gg)
#pragma unroll
            for (int tf = 0; tf < 4; ++tf)
#pragma unroll
                for (int kc = 0; kc < 2; ++kc)
                    st[gg][tf] = __builtin_amdgcn_mfma_f32_16x16x32_bf16(kf[tf][kc], qf[gg][kc], st[gg][tf], 0, 0, 0);

        // online softmax per q-row (4-lane groups: lane ^ 16, ^ 32)
#pragma unroll
        for (int gg = 0; gg < 2; ++gg) {
            float tmax = -3e30f;
#pragma unroll
            for (int tf = 0; tf < 4; ++tf)
#pragma unroll
                for (int i = 0; i < 4; ++i) tmax = fmaxf(tmax, st[gg][tf][i]);
            tmax *= scale;
            tmax = fmaxf(tmax, __shfl_xor(tmax, 16));
            tmax = fmaxf(tmax, __shfl_xor(tmax, 32));
            const float mnew = fmaxf(mrow[gg], tmax);
            const float corr = __expf(mrow[gg] - mnew);
            float psum = 0.f;
            const int row = gg * 16 + r;
#pragma unroll
            for (int tf = 0; tf < 4; ++tf) {
                float p0 = __expf(st[gg][tf][0] * scale - mnew);
                float p1 = __expf(st[gg][tf][1] * scale - mnew);
                float p2 = __expf(st[gg][tf][2] * scale - mnew);
                float p3 = __expf(st[gg][tf][3] * scale - mnew);
                psum += p0 + p1 + p2 + p3;
                ushort4 pk;
                pk.x = f2bf(p0); pk.y = f2bf(p1); pk.z = f2bf(p2); pk.w = f2bf(p3);
                const int cb = (tf * 32 + g * 8) ^ ((row & 7) << 4);   // XOR swizzle
                *(ushort4*)((char*)Pw + row * 128 + cb) = pk;
            }
            psum += __shfl_xor(psum, 16);
            psum += __shfl_xor(psum, 32);
            ell[gg] = ell[gg] * corr + psum;
            mrow[gg] = mnew;
#pragma unroll
            for (int mf = 0; mf < 4; ++mf)
#pragma unroll
                for (int i = 0; i < 4; ++i) oacc[gg][mf][i] *= corr;
        }

        // V fragments (A-operand of PV): vf[mf][kc], contiguous in Vt
        bf16x8 vf[4][2];
#pragma unroll
        for (int mf = 0; mf < 4; ++mf)
#pragma unroll
            for (int kc = 0; kc < 2; ++kc)
                vf[mf][kc] = *(const bf16x8*)&Vh[(size_t)(mf * 16 + r) * 2048 + t0 + kc * 32 + g * 8];

        // O^T += V^T * P^T
#pragma unroll
        for (int gg = 0; gg < 2; ++gg) {
            const int row = gg * 16 + r;
#pragma unroll
            for (int kc = 0; kc < 2; ++kc) {
                const int cb = (kc * 64 + g * 16) ^ ((row & 7) << 4);
                const bf16x8 pf = *(const bf16x8*)((const char*)Pw + row * 128 + cb);
#pragma unroll
                for (int mf = 0; mf < 4; ++mf)
                    oacc[gg][mf] = __builtin_amdgcn_mfma_f32_16x16x32_bf16(vf[mf][kc], pf, oacc[gg][mf], 0, 0, 0);
            }
        }
    }

    // epilogue: AO[b][q][h*64+dv] = O^T[dv][q] / ell[q]
#pragma unroll
    for (int gg = 0; gg < 2; ++gg) {
        const float inv = 1.f / ell[gg];
        const int q = qbase + gg * 16 + r;
#pragma unroll
        for (int mf = 0; mf < 4; ++mf) {
            ushort4 o;
            o.x = f2bf(oacc[gg][mf][0] * inv);
            o.y = f2bf(oacc[gg][mf][1] * inv);
            o.z = f2bf(oacc[gg][mf][2] * inv);
            o.w = f2bf(oacc[gg][mf][3] * inv);
            *(ushort4*)&AO[(size_t)(b * 2048 + q) * 1024 + h * 64 + mf * 16 + g * 4] = o;
        }
    }
}

// ---------------------------------------------------------------------------
extern "C" void kernel_launch(void* const* d_in, const int* in_sizes, int n_in,
                              void* d_out, int out_size, void* d_ws, size_t ws_size,
                              hipStream_t stream) {
    const float* q_f  = (const float*)d_in[0];
    const float* k_f  = (const float*)d_in[1];
    const float* v_f  = (const float*)d_in[2];
    const float* Wq_w = (const float*)d_in[3];
    const float* Wq_b = (const float*)d_in[4];
    const float* Wk_w = (const float*)d_in[5];
    const float* Wk_b = (const float*)d_in[6];
    const float* Wv_w = (const float*)d_in[7];
    const float* Wv_b = (const float*)d_in[8];
    const float* Wo_w = (const float*)d_in[9];
    const float* Wo_b = (const float*)d_in[10];
    float* out = (float*)d_out;
    char* ws = (char*)d_ws;

    const size_t MB = 1ull << 20;
    ushort* qb  = (ushort*)(ws);                 // 16 MB
    ushort* kb  = (ushort*)(ws + 16 * MB);       // 16 MB
    ushort* vb  = (ushort*)(ws + 32 * MB);       // 16 MB
    ushort* WqT = (ushort*)(ws + 48 * MB);       // 2 MB
    ushort* WkT = (ushort*)(ws + 50 * MB);       // 2 MB
    ushort* WvT = (ushort*)(ws + 52 * MB);       // 2 MB
    ushort* WoT = (ushort*)(ws + 54 * MB);       // 2 MB
    ushort* Qp  = (ushort*)(ws + 56 * MB);       // 16 MB
    ushort* Kp  = (ushort*)(ws + 72 * MB);       // 16 MB
    ushort* Vt  = (ushort*)(ws + 88 * MB);       // 16 MB  (end: 104 MB)
    ushort* AO  = qb;                            // reuse (qb dead after stage 2)

    const int n4 = (4 * 2048 * 1024) / 4;
    convert_bf16<<<2048, 256, 0, stream>>>(q_f, qb, n4);
    convert_bf16<<<2048, 256, 0, stream>>>(k_f, kb, n4);
    convert_bf16<<<2048, 256, 0, stream>>>(v_f, vb, n4);

    dim3 tg(16, 16);
    transpose_w<<<tg, 256, 0, stream>>>(Wq_w, WqT);
    transpose_w<<<tg, 256, 0, stream>>>(Wk_w, WkT);
    transpose_w<<<tg, 256, 0, stream>>>(Wv_w, WvT);
    transpose_w<<<tg, 256, 0, stream>>>(Wv_w, WvT);
    transpose_w<<<tg, 256, 0, stream>>>(Wo_w, WoT);

    dim3 gg(8, 64);
    gemm_bt<0><<<gg, 256, 0, stream>>>(qb, WqT, Wq_b, Qp, nullptr);
    gemm_bt<0><<<gg, 256, 0, stream>>>(kb, WkT, Wk_b, Kp, nullptr);
    gemm_bt<1><<<gg, 256, 0, stream>>>(vb, WvT, Wv_b, Vt, nullptr);

    attn_kernel<<<dim3(16, 16, 4), 256, 0, stream>>>(Qp, Kp, Vt, AO);

    gemm_bt<2><<<gg, 256, 0, stream>>>(AO, WoT, Wo_b, nullptr, out);
}

// Round 4
// 283.023 us; speedup vs baseline: 1.6564x; 1.6564x over previous
//
#include <hip/hip_runtime.h>
#include <hip/hip_bf16.h>
#include <cstdint>

// ---------------------------------------------------------------------------
// MultiHeadAttention: B=4 S=2048 D=1024 H=16 DQ=DV=64
//   1) cast q/k/v fp32->bf16; transpose Wq/Wk/Wv/Wo to (N,K) bf16
//   2) GEMM (8192x1024x1024) x3 -> Qp (scaled by 1/sqrt(S)*log2e), Kp,
//      Vt (per-head transposed bf16 Vt[b][h][dv][s])
//   3) flash attention, LDS-staged double-buffered K/V, exp2-domain softmax
//   4) GEMM (8192x1024x1024) + bias -> fp32 out
// ---------------------------------------------------------------------------

typedef __attribute__((ext_vector_type(4))) float f32x4;
typedef __attribute__((ext_vector_type(8))) short bf16x8;

#define GLB const __attribute__((address_space(1))) void*
#define LDS __attribute__((address_space(3))) void*

__device__ __forceinline__ ushort f2bf(float f) {
    uint32_t u = __builtin_bit_cast(uint32_t, f);
    u += 0x7fffu + ((u >> 16) & 1u);   // round-to-nearest-even
    return (ushort)(u >> 16);
}

// ---------------- stage 1a: fp32 -> bf16 (vectorized) ----------------------
__global__ void convert_bf16(const float* __restrict__ in, ushort* __restrict__ out, int n4) {
    for (int i = blockIdx.x * blockDim.x + threadIdx.x; i < n4; i += gridDim.x * blockDim.x) {
        float4 v = reinterpret_cast<const float4*>(in)[i];
        ushort4 o;
        o.x = f2bf(v.x); o.y = f2bf(v.y); o.z = f2bf(v.z); o.w = f2bf(v.w);
        reinterpret_cast<ushort4*>(out)[i] = o;
    }
}

// ---------------- stage 1b: W (K=1024,N=1024) fp32 -> WT (N,K) bf16 --------
__global__ void transpose_w(const float* __restrict__ in, ushort* __restrict__ out) {
    __shared__ float tile[64][65];
    const int tx = threadIdx.x & 63, ty = threadIdx.x >> 6;
    const int nb = blockIdx.x * 64, kb = blockIdx.y * 64;
#pragma unroll
    for (int i = ty; i < 64; i += 4)
        tile[i][tx] = in[(size_t)(kb + i) * 1024 + nb + tx];
    __syncthreads();
#pragma unroll
    for (int i = ty; i < 64; i += 4)
        out[(size_t)(nb + i) * 1024 + kb + tx] = f2bf(tile[tx][i]);
}

// ---------------- stage 2/4: GEMM  C = A(M,K) * BT(N,K)^T + bias -----------
// MODE 0: bf16 row-major out (scaled by oscale).  MODE 1: V -> Vt[b][h][dv][s].
// MODE 2: fp32 out.
template <int MODE>
__global__ __launch_bounds__(256) void gemm_bt(const ushort* __restrict__ A,
                                               const ushort* __restrict__ BT,
                                               const float* __restrict__ bias,
                                               ushort* __restrict__ Cb,
                                               float* __restrict__ Cf,
                                               float oscale) {
    constexpr int K = 1024, N = 1024;
    __shared__ ushort As[128 * 32];
    __shared__ ushort Bs[128 * 32];
    const int tid = threadIdx.x;
    const int lane = tid & 63;
    const int wave = tid >> 6, wr = wave >> 1, wc = wave & 1;
    const int r = lane & 15, g = lane >> 4;
    const int mb = blockIdx.y * 128, nb = blockIdx.x * 128;

    f32x4 acc[4][4] = {};

    for (int k0 = 0; k0 < K; k0 += 32) {
#pragma unroll
        for (int j = 0; j < 2; ++j) {
            const int t = j * 256 + tid;
            const ushort* ga = A  + (size_t)(mb + (t >> 2)) * K + k0 + (t & 3) * 8;
            const ushort* gb = BT + (size_t)(nb + (t >> 2)) * K + k0 + (t & 3) * 8;
            const int lo = (j * 256 + (tid & ~63)) * 8;   // wave-uniform elem offset
            __builtin_amdgcn_global_load_lds((GLB)ga, (LDS)(As + lo), 16, 0, 0);
            __builtin_amdgcn_global_load_lds((GLB)gb, (LDS)(Bs + lo), 16, 0, 0);
        }
        __syncthreads();

        bf16x8 af[4], bfr[4];
#pragma unroll
        for (int i = 0; i < 4; ++i) {
            af[i]  = *(const bf16x8*)&As[(wr * 64 + i * 16 + r) * 32 + g * 8];
            bfr[i] = *(const bf16x8*)&Bs[(wc * 64 + i * 16 + r) * 32 + g * 8];
        }
#pragma unroll
        for (int mi = 0; mi < 4; ++mi)
#pragma unroll
            for (int ni = 0; ni < 4; ++ni)
                acc[mi][ni] = __builtin_amdgcn_mfma_f32_16x16x32_bf16(af[mi], bfr[ni], acc[mi][ni], 0, 0, 0);
        __syncthreads();
    }

#pragma unroll
    for (int ni = 0; ni < 4; ++ni) {
        const int col = nb + wc * 64 + ni * 16 + r;
        const float bv = bias[col];
#pragma unroll
        for (int mi = 0; mi < 4; ++mi) {
            const int m0 = mb + wr * 64 + mi * 16 + g * 4;
            if (MODE == 0) {
#pragma unroll
                for (int i = 0; i < 4; ++i)
                    Cb[(size_t)(m0 + i) * N + col] = f2bf((acc[mi][ni][i] + bv) * oscale);
            } else if (MODE == 1) {
                const int b = m0 >> 11, s = m0 & 2047;
                const int h = col >> 6, dv = col & 63;
                ushort4 o;
                o.x = f2bf(acc[mi][ni][0] + bv);
                o.y = f2bf(acc[mi][ni][1] + bv);
                o.z = f2bf(acc[mi][ni][2] + bv);
                o.w = f2bf(acc[mi][ni][3] + bv);
                *(ushort4*)&Cb[(((size_t)(b * 16 + h) * 64 + dv) << 11) + s] = o;
            } else {
#pragma unroll
                for (int i = 0; i < 4; ++i)
                    Cf[(size_t)(m0 + i) * N + col] = acc[mi][ni][i] + bv;
            }
        }
    }
}

// ---------------- stage 3: flash attention ---------------------------------
// grid (qtile=8, h=16, b=4) = 512 blocks; block 512 thr (8 waves, 32 q-rows ea)
// K,V tiles (64 kv-rows) double-buffered in LDS, staged via global_load_lds
// with pre-swizzled source (st-16x32-style XOR swizzle on 16B slots).
// Qp pre-scaled by 1/sqrt(S)*log2e -> softmax in exp2 domain, defer-max THR=8.
__global__ __launch_bounds__(512, 4) void attn_kernel(const ushort* __restrict__ Qp,
                                                      const ushort* __restrict__ Kp,
                                                      const ushort* __restrict__ Vt,
                                                      ushort* __restrict__ AO) {
    const int tid = threadIdx.x;
    const int lane = tid & 63, wave = tid >> 6;
    const int r = lane & 15, g = lane >> 4;
    const int qt = blockIdx.x, h = blockIdx.y, b = blockIdx.z;
    const int qbase = qt * 256 + wave * 32;

    const ushort* Qh = Qp + (size_t)b * 2048 * 1024 + h * 64;
    const ushort* Kh = Kp + (size_t)b * 2048 * 1024 + h * 64;
    const ushort* Vh = Vt + ((size_t)(b * 16 + h)) * 64 * 2048;

    __shared__ ushort Ks[2][64 * 64];   // [buf][row*64 + col], XOR-swizzled
    __shared__ ushort Vs[2][64 * 64];
    __shared__ ushort Pl[8][32 * 64];   // per-wave P tile
    ushort* Pw = (ushort*)Pl[wave];

    // staging geometry: thread tid stages 16B; row = tid>>3, swizzled source col
    const int srow = tid >> 3;                                  // 0..63
    const int scb  = ((tid & 7) * 16) ^ ((srow & 7) << 4);      // swizzled byte col
    const ushort* gKb = Kh + (size_t)srow * 1024 + (scb >> 1);
    const ushort* gVb = Vh + (size_t)srow * 2048 + (scb >> 1);
    const int wlds = wave * 512;                                // wave-uniform elems

    // Q fragments (B-operand of swapped QK): qf[gg][kc]
    bf16x8 qf[2][2];
#pragma unroll
    for (int gg = 0; gg < 2; ++gg)
#pragma unroll
        for (int kc = 0; kc < 2; ++kc)
            qf[gg][kc] = *(const bf16x8*)&Qh[(size_t)(qbase + gg * 16 + r) * 1024 + kc * 32 + g * 8];

    f32x4 oacc[2][4] = {};
    float mrow[2] = {-1e30f, -1e30f};
    float ell[2] = {0.f, 0.f};

    // prologue: stage tile 0 into buf 0
    __builtin_amdgcn_global_load_lds((GLB)gKb, (LDS)(Ks[0] + wlds), 16, 0, 0);
    __builtin_amdgcn_global_load_lds((GLB)gVb, (LDS)(Vs[0] + wlds), 16, 0, 0);
    __syncthreads();

    for (int t0 = 0; t0 < 2048; t0 += 64) {
        const int cur = (t0 >> 6) & 1;
        if (t0 + 64 < 2048) {   // issue next-tile stage; overlaps compute below
            __builtin_amdgcn_global_load_lds((GLB)(gKb + (size_t)(t0 + 64) * 1024),
                                             (LDS)(Ks[cur ^ 1] + wlds), 16, 0, 0);
            __builtin_amdgcn_global_load_lds((GLB)(gVb + (t0 + 64)),
                                             (LDS)(Vs[cur ^ 1] + wlds), 16, 0, 0);
        }

        // K fragments from LDS (swizzled read)
        bf16x8 kf[4][2];
#pragma unroll
        for (int tf = 0; tf < 4; ++tf)
#pragma unroll
            for (int kc = 0; kc < 2; ++kc) {
                const int row = tf * 16 + r;
                const int by = row * 128 + ((kc * 64 + g * 16) ^ ((row & 7) << 4));
                kf[tf][kc] = *(const bf16x8*)((const char*)Ks[cur] + by);
            }

        // St = K * Q^T : st[gg][tf], t = tf*16 + g*4 + i, q = gg*16 + r
        f32x4 st[2][4] = {};
#pragma unroll
        for (int gg = 0; gg < 2; ++gg)
#pragma unroll
            for (int tf = 0; tf < 4; ++tf)
#pragma unroll
                for (int kc = 0; kc < 2; ++kc)
                    st[gg][tf] = __builtin_amdgcn_mfma_f32_16x16x32_bf16(kf[tf][kc], qf[gg][kc], st[gg][tf], 0, 0, 0);

        // ---- online softmax (exp2 domain; Q pre-scaled) ----
        float tmax[2];
#pragma unroll
        for (int gg = 0; gg < 2; ++gg) {
            float t = st[gg][0][0];
#pragma unroll
            for (int tf = 0; tf < 4; ++tf)
#pragma unroll
                for (int i = 0; i < 4; ++i) t = fmaxf(t, st[gg][tf][i]);
            t = fmaxf(t, __shfl_xor(t, 16));
            t = fmaxf(t, __shfl_xor(t, 32));
            tmax[gg] = t;
        }
        // defer-max: skip rescale while growth bounded (P <= 2^8)
        const bool defer = __all((tmax[0] <= mrow[0] + 8.f) & (tmax[1] <= mrow[1] + 8.f));
        if (!defer) {
#pragma unroll
            for (int gg = 0; gg < 2; ++gg) {
                const float mnew = fmaxf(mrow[gg], tmax[gg]);
                const float corr = __builtin_amdgcn_exp2f(mrow[gg] - mnew);
                ell[gg] *= corr;
#pragma unroll
                for (int mf = 0; mf < 4; ++mf)
#pragma unroll
                    for (int i = 0; i < 4; ++i) oacc[gg][mf][i] *= corr;
                mrow[gg] = mnew;
            }
        }
#pragma unroll
        for (int gg = 0; gg < 2; ++gg) {
            const int row = gg * 16 + r;
            float psum = 0.f;
#pragma unroll
            for (int tf = 0; tf < 4; ++tf) {
                const float p0 = __builtin_amdgcn_exp2f(st[gg][tf][0] - mrow[gg]);
                const float p1 = __builtin_amdgcn_exp2f(st[gg][tf][1] - mrow[gg]);
                const float p2 = __builtin_amdgcn_exp2f(st[gg][tf][2] - mrow[gg]);
                const float p3 = __builtin_amdgcn_exp2f(st[gg][tf][3] - mrow[gg]);
                psum += p0 + p1 + p2 + p3;
                ushort4 pk;
                pk.x = f2bf(p0); pk.y = f2bf(p1); pk.z = f2bf(p2); pk.w = f2bf(p3);
                const int cb = (tf * 32 + g * 8) ^ ((row & 7) << 4);
                *(ushort4*)((char*)Pw + row * 128 + cb) = pk;
            }
            psum += __shfl_xor(psum, 16);
            psum += __shfl_xor(psum, 32);
            ell[gg] += psum;
        }

        // V fragments from LDS (swizzled read)
        bf16x8 vf[4][2];
#pragma unroll
        for (int mf = 0; mf < 4; ++mf)
#pragma unroll
            for (int kc = 0; kc < 2; ++kc) {
                const int row = mf * 16 + r;
                const int by = row * 128 + ((kc * 64 + g * 16) ^ ((row & 7) << 4));
                vf[mf][kc] = *(const bf16x8*)((const char*)Vs[cur] + by);
            }

        // O^T += V^T * P^T
#pragma unroll
        for (int gg = 0; gg < 2; ++gg) {
            const int row = gg * 16 + r;
#pragma unroll
            for (int kc = 0; kc < 2; ++kc) {
                const int cb = (kc * 64 + g * 16) ^ ((row & 7) << 4);
                const bf16x8 pf = *(const bf16x8*)((const char*)Pw + row * 128 + cb);
#pragma unroll
                for (int mf = 0; mf < 4; ++mf)
                    oacc[gg][mf] = __builtin_amdgcn_mfma_f32_16x16x32_bf16(vf[mf][kc], pf, oacc[gg][mf], 0, 0, 0);
            }
        }

        // drain stage (compiler emits vmcnt(0) before s_barrier) + buffer flip
        __syncthreads();
    }

    // epilogue: AO[b][q][h*64+dv] = O^T[dv][q] / ell[q]
#pragma unroll
    for (int gg = 0; gg < 2; ++gg) {
        const float inv = 1.f / ell[gg];
        const int q = qbase + gg * 16 + r;
#pragma unroll
        for (int mf = 0; mf < 4; ++mf) {
            ushort4 o;
            o.x = f2bf(oacc[gg][mf][0] * inv);
            o.y = f2bf(oacc[gg][mf][1] * inv);
            o.z = f2bf(oacc[gg][mf][2] * inv);
            o.w = f2bf(oacc[gg][mf][3] * inv);
            *(ushort4*)&AO[(size_t)(b * 2048 + q) * 1024 + h * 64 + mf * 16 + g * 4] = o;
        }
    }
}

// ---------------------------------------------------------------------------
extern "C" void kernel_launch(void* const* d_in, const int* in_sizes, int n_in,
                              void* d_out, int out_size, void* d_ws, size_t ws_size,
                              hipStream_t stream) {
    const float* q_f  = (const float*)d_in[0];
    const float* k_f  = (const float*)d_in[1];
    const float* v_f  = (const float*)d_in[2];
    const float* Wq_w = (const float*)d_in[3];
    const float* Wq_b = (const float*)d_in[4];
    const float* Wk_w = (const float*)d_in[5];
    const float* Wk_b = (const float*)d_in[6];
    const float* Wv_w = (const float*)d_in[7];
    const float* Wv_b = (const float*)d_in[8];
    const float* Wo_w = (const float*)d_in[9];
    const float* Wo_b = (const float*)d_in[10];
    float* out = (float*)d_out;
    char* ws = (char*)d_ws;

    const size_t MB = 1ull << 20;
    ushort* qb  = (ushort*)(ws);                 // 16 MB
    ushort* kb  = (ushort*)(ws + 16 * MB);       // 16 MB
    ushort* vb  = (ushort*)(ws + 32 * MB);       // 16 MB
    ushort* WqT = (ushort*)(ws + 48 * MB);       // 2 MB
    ushort* WkT = (ushort*)(ws + 50 * MB);       // 2 MB
    ushort* WvT = (ushort*)(ws + 52 * MB);       // 2 MB
    ushort* WoT = (ushort*)(ws + 54 * MB);       // 2 MB
    ushort* Qp  = (ushort*)(ws + 56 * MB);       // 16 MB
    ushort* Kp  = (ushort*)(ws + 72 * MB);       // 16 MB
    ushort* Vt  = (ushort*)(ws + 88 * MB);       // 16 MB  (end: 104 MB)
    ushort* AO  = qb;                            // reuse (qb dead after stage 2)

    const int n4 = (4 * 2048 * 1024) / 4;
    convert_bf16<<<2048, 256, 0, stream>>>(q_f, qb, n4);
    convert_bf16<<<2048, 256, 0, stream>>>(k_f, kb, n4);
    convert_bf16<<<2048, 256, 0, stream>>>(v_f, vb, n4);

    dim3 tg(16, 16);
    transpose_w<<<tg, 256, 0, stream>>>(Wq_w, WqT);
    transpose_w<<<tg, 256, 0, stream>>>(Wk_w, WkT);
    transpose_w<<<tg, 256, 0, stream>>>(Wv_w, WvT);
    transpose_w<<<tg, 256, 0, stream>>>(Wo_w, WoT);

    // fold attention scale (1/sqrt(2048)) and log2(e) into Q projection
    constexpr float QSCALE = (float)(1.4426950408889634 / 45.254833995939045);

    dim3 gg(8, 64);
    gemm_bt<0><<<gg, 256, 0, stream>>>(qb, WqT, Wq_b, Qp, nullptr, QSCALE);
    gemm_bt<0><<<gg, 256, 0, stream>>>(kb, WkT, Wk_b, Kp, nullptr, 1.0f);
    gemm_bt<1><<<gg, 256, 0, stream>>>(vb, WvT, Wv_b, Vt, nullptr, 1.0f);

    attn_kernel<<<dim3(8, 16, 4), 512, 0, stream>>>(Qp, Kp, Vt, AO);

    gemm_bt<2><<<gg, 256, 0, stream>>>(AO, WoT, Wo_b, nullptr, out, 1.0f);
}

// Round 5
// 248.088 us; speedup vs baseline: 1.8896x; 1.1408x over previous
//
#include <hip/hip_runtime.h>
#include <hip/hip_bf16.h>
#include <cstdint>

// ---------------------------------------------------------------------------
// MultiHeadAttention: B=4 S=2048 D=1024 H=16 DQ=DV=64
//   1) cast q/k/v fp32->bf16 (fused x3); transpose Wq/Wk/Wv/Wo (fused x4)
//   2) GEMM (8192x1024x1024) x3 -> Qp (pre-scaled log2e/sqrt(S)), Kp, Vt
//   3) flash attention: LDS dbuf K/V, exp2 softmax, cvt_pk P-pack,
//      XCD-swizzled grid, setprio around MFMA
//   4) GEMM + bias -> fp32 out
// ---------------------------------------------------------------------------

typedef __attribute__((ext_vector_type(4))) float f32x4;
typedef __attribute__((ext_vector_type(8))) short bf16x8;

#define GLB const __attribute__((address_space(1))) void*
#define LDS __attribute__((address_space(3))) void*

__device__ __forceinline__ ushort f2bf(float f) {
    uint32_t u = __builtin_bit_cast(uint32_t, f);
    u += 0x7fffu + ((u >> 16) & 1u);   // round-to-nearest-even
    return (ushort)(u >> 16);
}

// one v_cvt_pk_bf16_f32: packs 2 fp32 -> 2 bf16 in a u32 (RNE)
__device__ __forceinline__ uint32_t cvt_pk_bf16(float lo, float hi) {
    uint32_t r;
    asm("v_cvt_pk_bf16_f32 %0, %1, %2" : "=v"(r) : "v"(lo), "v"(hi));
    return r;
}

// ---------------- stage 1a: fp32 -> bf16, 3 tensors fused ------------------
__global__ void convert3(const float* __restrict__ a, const float* __restrict__ b,
                         const float* __restrict__ c,
                         ushort* __restrict__ oa, ushort* __restrict__ ob,
                         ushort* __restrict__ oc, int n4) {
    const float* in = blockIdx.y == 0 ? a : blockIdx.y == 1 ? b : c;
    ushort* out     = blockIdx.y == 0 ? oa : blockIdx.y == 1 ? ob : oc;
    for (int i = blockIdx.x * blockDim.x + threadIdx.x; i < n4; i += gridDim.x * blockDim.x) {
        float4 v = reinterpret_cast<const float4*>(in)[i];
        ushort4 o;
        o.x = f2bf(v.x); o.y = f2bf(v.y); o.z = f2bf(v.z); o.w = f2bf(v.w);
        reinterpret_cast<ushort4*>(out)[i] = o;
    }
}

// ---------------- stage 1b: W (K=1024,N=1024) fp32 -> WT (N,K) bf16, x4 ----
__global__ void transpose_w4(const float* __restrict__ w0, const float* __restrict__ w1,
                             const float* __restrict__ w2, const float* __restrict__ w3,
                             ushort* __restrict__ o0, ushort* __restrict__ o1,
                             ushort* __restrict__ o2, ushort* __restrict__ o3) {
    const float* in = blockIdx.z == 0 ? w0 : blockIdx.z == 1 ? w1 : blockIdx.z == 2 ? w2 : w3;
    ushort* out     = blockIdx.z == 0 ? o0 : blockIdx.z == 1 ? o1 : blockIdx.z == 2 ? o2 : o3;
    __shared__ float tile[64][65];
    const int tx = threadIdx.x & 63, ty = threadIdx.x >> 6;
    const int nb = blockIdx.x * 64, kb = blockIdx.y * 64;
#pragma unroll
    for (int i = ty; i < 64; i += 4)
        tile[i][tx] = in[(size_t)(kb + i) * 1024 + nb + tx];
    __syncthreads();
#pragma unroll
    for (int i = ty; i < 64; i += 4)
        out[(size_t)(nb + i) * 1024 + kb + tx] = f2bf(tile[tx][i]);
}

// ---------------- stage 2/4: GEMM  C = A(M,K) * BT(N,K)^T + bias -----------
// 1-D grid 512, XCD-swizzled: XCD x covers y-panels [x*8, x*8+8) for all x.
// MODE 0: bf16 row-major out (scaled).  MODE 1: V -> Vt[b][h][dv][s].
// MODE 2: fp32 out.
template <int MODE>
__global__ __launch_bounds__(256) void gemm_bt(const ushort* __restrict__ A,
                                               const ushort* __restrict__ BT,
                                               const float* __restrict__ bias,
                                               ushort* __restrict__ Cb,
                                               float* __restrict__ Cf,
                                               float oscale) {
    constexpr int K = 1024, N = 1024;
    __shared__ ushort As[128 * 32];
    __shared__ ushort Bs[128 * 32];
    const int tid = threadIdx.x;
    const int lane = tid & 63;
    const int wave = tid >> 6, wr = wave >> 1, wc = wave & 1;
    const int r = lane & 15, g = lane >> 4;
    // XCD swizzle: id = j*8 + xcd; per XCD: 8 M-panels x all 8 N-blocks (A
    // slice 2MB + B 2MB = L2-resident)
    const int id = blockIdx.x;
    const int xcd = id & 7, j = id >> 3;
    const int bx = j >> 3, by = xcd * 8 + (j & 7);
    const int mb = by * 128, nb = bx * 128;

    f32x4 acc[4][4] = {};

    for (int k0 = 0; k0 < K; k0 += 32) {
#pragma unroll
        for (int jj = 0; jj < 2; ++jj) {
            const int t = jj * 256 + tid;
            const ushort* ga = A  + (size_t)(mb + (t >> 2)) * K + k0 + (t & 3) * 8;
            const ushort* gb = BT + (size_t)(nb + (t >> 2)) * K + k0 + (t & 3) * 8;
            const int lo = (jj * 256 + (tid & ~63)) * 8;   // wave-uniform elem offset
            __builtin_amdgcn_global_load_lds((GLB)ga, (LDS)(As + lo), 16, 0, 0);
            __builtin_amdgcn_global_load_lds((GLB)gb, (LDS)(Bs + lo), 16, 0, 0);
        }
        __syncthreads();

        bf16x8 af[4], bfr[4];
#pragma unroll
        for (int i = 0; i < 4; ++i) {
            af[i]  = *(const bf16x8*)&As[(wr * 64 + i * 16 + r) * 32 + g * 8];
            bfr[i] = *(const bf16x8*)&Bs[(wc * 64 + i * 16 + r) * 32 + g * 8];
        }
        __builtin_amdgcn_s_setprio(1);
#pragma unroll
        for (int mi = 0; mi < 4; ++mi)
#pragma unroll
            for (int ni = 0; ni < 4; ++ni)
                acc[mi][ni] = __builtin_amdgcn_mfma_f32_16x16x32_bf16(af[mi], bfr[ni], acc[mi][ni], 0, 0, 0);
        __builtin_amdgcn_s_setprio(0);
        __syncthreads();
    }

#pragma unroll
    for (int ni = 0; ni < 4; ++ni) {
        const int col = nb + wc * 64 + ni * 16 + r;
        const float bv = bias[col];
#pragma unroll
        for (int mi = 0; mi < 4; ++mi) {
            const int m0 = mb + wr * 64 + mi * 16 + g * 4;
            if (MODE == 0) {
#pragma unroll
                for (int i = 0; i < 4; ++i)
                    Cb[(size_t)(m0 + i) * N + col] = f2bf((acc[mi][ni][i] + bv) * oscale);
            } else if (MODE == 1) {
                const int b = m0 >> 11, s = m0 & 2047;
                const int h = col >> 6, dv = col & 63;
                ushort4 o;
                o.x = f2bf(acc[mi][ni][0] + bv);
                o.y = f2bf(acc[mi][ni][1] + bv);
                o.z = f2bf(acc[mi][ni][2] + bv);
                o.w = f2bf(acc[mi][ni][3] + bv);
                *(ushort4*)&Cb[(((size_t)(b * 16 + h) * 64 + dv) << 11) + s] = o;
            } else {
#pragma unroll
                for (int i = 0; i < 4; ++i)
                    Cf[(size_t)(m0 + i) * N + col] = acc[mi][ni][i] + bv;
            }
        }
    }
}

// ---------------- stage 3: flash attention ---------------------------------
// 1-D grid 512 (XCD-swizzled: 8 q-tiles of a (b,h) share an XCD -> K/V
// L2-resident per XCD: 8 heads x 512KB = 4MB). Block 512 thr = 8 waves.
__global__ __launch_bounds__(512, 4) void attn_kernel(const ushort* __restrict__ Qp,
                                                      const ushort* __restrict__ Kp,
                                                      const ushort* __restrict__ Vt,
                                                      ushort* __restrict__ AO) {
    const int tid = threadIdx.x;
    const int lane = tid & 63, wave = tid >> 6;
    const int r = lane & 15, g = lane >> 4;
    // XCD-bijective decomposition (512 = 8 xcd x 8 grp x 8 qt)
    const int id = blockIdx.x;
    const int xcd = id & 7, j = id >> 3;
    const int qt = j & 7;
    const int grp = xcd * 8 + (j >> 3);      // (b,h) group 0..63
    const int h = grp & 15, b = grp >> 4;
    const int qbase = qt * 256 + wave * 32;

    const ushort* Qh = Qp + (size_t)b * 2048 * 1024 + h * 64;
    const ushort* Kh = Kp + (size_t)b * 2048 * 1024 + h * 64;
    const ushort* Vh = Vt + ((size_t)(b * 16 + h)) * 64 * 2048;

    __shared__ ushort Ks[2][64 * 64];   // [buf][row*64 + col], XOR-swizzled
    __shared__ ushort Vs[2][64 * 64];
    __shared__ ushort Pl[8][32 * 64];   // per-wave P tile
    ushort* Pw = (ushort*)Pl[wave];

    // staging geometry: thread tid stages 16B; row = tid>>3, swizzled source col
    const int srow = tid >> 3;                                  // 0..63
    const int scb  = ((tid & 7) * 16) ^ ((srow & 7) << 4);      // swizzled byte col
    const ushort* gKb = Kh + (size_t)srow * 1024 + (scb >> 1);
    const ushort* gVb = Vh + (size_t)srow * 2048 + (scb >> 1);
    const int wlds = wave * 512;                                // wave-uniform elems

    // Q fragments (B-operand of swapped QK): qf[gg][kc]
    bf16x8 qf[2][2];
#pragma unroll
    for (int gg = 0; gg < 2; ++gg)
#pragma unroll
        for (int kc = 0; kc < 2; ++kc)
            qf[gg][kc] = *(const bf16x8*)&Qh[(size_t)(qbase + gg * 16 + r) * 1024 + kc * 32 + g * 8];

    f32x4 oacc[2][4] = {};
    float mrow[2] = {-1e30f, -1e30f};
    float ell[2] = {0.f, 0.f};

    // prologue: stage tile 0 into buf 0
    __builtin_amdgcn_global_load_lds((GLB)gKb, (LDS)(Ks[0] + wlds), 16, 0, 0);
    __builtin_amdgcn_global_load_lds((GLB)gVb, (LDS)(Vs[0] + wlds), 16, 0, 0);
    __syncthreads();

    for (int t0 = 0; t0 < 2048; t0 += 64) {
        const int cur = (t0 >> 6) & 1;
        if (t0 + 64 < 2048) {   // issue next-tile stage; overlaps compute below
            __builtin_amdgcn_global_load_lds((GLB)(gKb + (size_t)(t0 + 64) * 1024),
                                             (LDS)(Ks[cur ^ 1] + wlds), 16, 0, 0);
            __builtin_amdgcn_global_load_lds((GLB)(gVb + (t0 + 64)),
                                             (LDS)(Vs[cur ^ 1] + wlds), 16, 0, 0);
        }

        // K fragments from LDS (swizzled read)
        bf16x8 kf[4][2];
#pragma unroll
        for (int tf = 0; tf < 4; ++tf)
#pragma unroll
            for (int kc = 0; kc < 2; ++kc) {
                const int row = tf * 16 + r;
                const int by = row * 128 + ((kc * 64 + g * 16) ^ ((row & 7) << 4));
                kf[tf][kc] = *(const bf16x8*)((const char*)Ks[cur] + by);
            }

        // St = K * Q^T : st[gg][tf], t = tf*16 + g*4 + i, q = gg*16 + r
        f32x4 st[2][4] = {};
        __builtin_amdgcn_s_setprio(1);
#pragma unroll
        for (int gg = 0; gg < 2; ++gg)
#pragma unroll
            for (int tf = 0; tf < 4; ++tf)
#pragma unroll
                for (int kc = 0; kc < 2; ++kc)
                    st[gg][tf] = __builtin_amdgcn_mfma_f32_16x16x32_bf16(kf[tf][kc], qf[gg][kc], st[gg][tf], 0, 0, 0);
        __builtin_amdgcn_s_setprio(0);

        // ---- online softmax (exp2 domain; Q pre-scaled) ----
        float tmax[2];
#pragma unroll
        for (int gg = 0; gg < 2; ++gg) {
            float m01 = fmaxf(fmaxf(st[gg][0][0], st[gg][0][1]), fmaxf(st[gg][0][2], st[gg][0][3]));
            float m23 = fmaxf(fmaxf(st[gg][1][0], st[gg][1][1]), fmaxf(st[gg][1][2], st[gg][1][3]));
            float m45 = fmaxf(fmaxf(st[gg][2][0], st[gg][2][1]), fmaxf(st[gg][2][2], st[gg][2][3]));
            float m67 = fmaxf(fmaxf(st[gg][3][0], st[gg][3][1]), fmaxf(st[gg][3][2], st[gg][3][3]));
            float t = fmaxf(fmaxf(m01, m23), fmaxf(m45, m67));
            t = fmaxf(t, __shfl_xor(t, 16));
            t = fmaxf(t, __shfl_xor(t, 32));
            tmax[gg] = t;
        }
        // defer-max: skip rescale while growth bounded (P <= 2^8)
        const bool defer = __all((tmax[0] <= mrow[0] + 8.f) & (tmax[1] <= mrow[1] + 8.f));
        if (!defer) {
#pragma unroll
            for (int gg = 0; gg < 2; ++gg) {
                const float mnew = fmaxf(mrow[gg], tmax[gg]);
                const float corr = __builtin_amdgcn_exp2f(mrow[gg] - mnew);
                ell[gg] *= corr;
#pragma unroll
                for (int mf = 0; mf < 4; ++mf)
#pragma unroll
                    for (int i = 0; i < 4; ++i) oacc[gg][mf][i] *= corr;
                mrow[gg] = mnew;
            }
        }
#pragma unroll
        for (int gg = 0; gg < 2; ++gg) {
            const int row = gg * 16 + r;
            float psum = 0.f;
#pragma unroll
            for (int tf = 0; tf < 4; ++tf) {
                const float p0 = __builtin_amdgcn_exp2f(st[gg][tf][0] - mrow[gg]);
                const float p1 = __builtin_amdgcn_exp2f(st[gg][tf][1] - mrow[gg]);
                const float p2 = __builtin_amdgcn_exp2f(st[gg][tf][2] - mrow[gg]);
                const float p3 = __builtin_amdgcn_exp2f(st[gg][tf][3] - mrow[gg]);
                psum += (p0 + p1) + (p2 + p3);
                uint2 pk;
                pk.x = cvt_pk_bf16(p0, p1);
                pk.y = cvt_pk_bf16(p2, p3);
                const int cb = (tf * 32 + g * 8) ^ ((row & 7) << 4);
                *(uint2*)((char*)Pw + row * 128 + cb) = pk;
            }
            psum += __shfl_xor(psum, 16);
            psum += __shfl_xor(psum, 32);
            ell[gg] += psum;
        }

        // V fragments from LDS (swizzled read)
        bf16x8 vf[4][2];
#pragma unroll
        for (int mf = 0; mf < 4; ++mf)
#pragma unroll
            for (int kc = 0; kc < 2; ++kc) {
                const int row = mf * 16 + r;
                const int by = row * 128 + ((kc * 64 + g * 16) ^ ((row & 7) << 4));
                vf[mf][kc] = *(const bf16x8*)((const char*)Vs[cur] + by);
            }

        // O^T += V^T * P^T
        __builtin_amdgcn_s_setprio(1);
#pragma unroll
        for (int gg = 0; gg < 2; ++gg) {
            const int row = gg * 16 + r;
#pragma unroll
            for (int kc = 0; kc < 2; ++kc) {
                const int cb = (kc * 64 + g * 16) ^ ((row & 7) << 4);
                const bf16x8 pf = *(const bf16x8*)((const char*)Pw + row * 128 + cb);
#pragma unroll
                for (int mf = 0; mf < 4; ++mf)
                    oacc[gg][mf] = __builtin_amdgcn_mfma_f32_16x16x32_bf16(vf[mf][kc], pf, oacc[gg][mf], 0, 0, 0);
            }
        }
        __builtin_amdgcn_s_setprio(0);

        // drain stage (compiler emits vmcnt(0) before s_barrier) + buffer flip
        __syncthreads();
    }

    // epilogue: AO[b][q][h*64+dv] = O^T[dv][q] / ell[q]
#pragma unroll
    for (int gg = 0; gg < 2; ++gg) {
        const float inv = 1.f / ell[gg];
        const int q = qbase + gg * 16 + r;
#pragma unroll
        for (int mf = 0; mf < 4; ++mf) {
            ushort4 o;
            o.x = f2bf(oacc[gg][mf][0] * inv);
            o.y = f2bf(oacc[gg][mf][1] * inv);
            o.z = f2bf(oacc[gg][mf][2] * inv);
            o.w = f2bf(oacc[gg][mf][3] * inv);
            *(ushort4*)&AO[(size_t)(b * 2048 + q) * 1024 + h * 64 + mf * 16 + g * 4] = o;
        }
    }
}

// ---------------------------------------------------------------------------
extern "C" void kernel_launch(void* const* d_in, const int* in_sizes, int n_in,
                              void* d_out, int out_size, void* d_ws, size_t ws_size,
                              hipStream_t stream) {
    const float* q_f  = (const float*)d_in[0];
    const float* k_f  = (const float*)d_in[1];
    const float* v_f  = (const float*)d_in[2];
    const float* Wq_w = (const float*)d_in[3];
    const float* Wq_b = (const float*)d_in[4];
    const float* Wk_w = (const float*)d_in[5];
    const float* Wk_b = (const float*)d_in[6];
    const float* Wv_w = (const float*)d_in[7];
    const float* Wv_b = (const float*)d_in[8];
    const float* Wo_w = (const float*)d_in[9];
    const float* Wo_b = (const float*)d_in[10];
    float* out = (float*)d_out;
    char* ws = (char*)d_ws;

    const size_t MB = 1ull << 20;
    ushort* qb  = (ushort*)(ws);                 // 16 MB
    ushort* kb  = (ushort*)(ws + 16 * MB);       // 16 MB
    ushort* vb  = (ushort*)(ws + 32 * MB);       // 16 MB
    ushort* WqT = (ushort*)(ws + 48 * MB);       // 2 MB
    ushort* WkT = (ushort*)(ws + 50 * MB);       // 2 MB
    ushort* WvT = (ushort*)(ws + 52 * MB);       // 2 MB
    ushort* WoT = (ushort*)(ws + 54 * MB);       // 2 MB
    ushort* Qp  = (ushort*)(ws + 56 * MB);       // 16 MB
    ushort* Kp  = (ushort*)(ws + 72 * MB);       // 16 MB
    ushort* Vt  = (ushort*)(ws + 88 * MB);       // 16 MB  (end: 104 MB)
    ushort* AO  = qb;                            // reuse (qb dead after stage 2)

    const int n4 = (4 * 2048 * 1024) / 4;
    convert3<<<dim3(1024, 3), 256, 0, stream>>>(q_f, k_f, v_f, qb, kb, vb, n4);

    transpose_w4<<<dim3(16, 16, 4), 256, 0, stream>>>(Wq_w, Wk_w, Wv_w, Wo_w,
                                                      WqT, WkT, WvT, WoT);

    // fold attention scale (1/sqrt(2048)) and log2(e) into Q projection
    constexpr float QSCALE = (float)(1.4426950408889634 / 45.254833995939045);

    gemm_bt<0><<<512, 256, 0, stream>>>(qb, WqT, Wq_b, Qp, nullptr, QSCALE);
    gemm_bt<0><<<512, 256, 0, stream>>>(kb, WkT, Wk_b, Kp, nullptr, 1.0f);
    gemm_bt<1><<<512, 256, 0, stream>>>(vb, WvT, Wv_b, Vt, nullptr, 1.0f);

    attn_kernel<<<512, 512, 0, stream>>>(Qp, Kp, Vt, AO);

    gemm_bt<2><<<512, 256, 0, stream>>>(AO, WoT, Wo_b, nullptr, out, 1.0f);
}

// Round 7
// 236.579 us; speedup vs baseline: 1.9815x; 1.0486x over previous
//
#include <hip/hip_runtime.h>
#include <hip/hip_bf16.h>
#include <cstdint>

// ---------------------------------------------------------------------------
// MultiHeadAttention: B=4 S=2048 D=1024 H=16 DQ=DV=64
//   1) cast q/k/v fp32->bf16 (fused x3); transpose Wq/Wk/Wv/Wo (fused x4)
//   2) one batched GEMM dispatch -> Qp (pre-scaled log2e/sqrt(S)), Kp, Vt
//   3) flash attention: LDS dbuf K/V, exp2 softmax + defer-max (round-5
//      proven path), cvt_pk P-pack, XCD-swizzled grid
//   4) GEMM + bias -> fp32 out
// ---------------------------------------------------------------------------

typedef __attribute__((ext_vector_type(4))) float f32x4;
typedef __attribute__((ext_vector_type(8))) short bf16x8;

#define GLB const __attribute__((address_space(1))) void*
#define LDS __attribute__((address_space(3))) void*

__device__ __forceinline__ ushort f2bf(float f) {
    uint32_t u = __builtin_bit_cast(uint32_t, f);
    u += 0x7fffu + ((u >> 16) & 1u);   // round-to-nearest-even
    return (ushort)(u >> 16);
}

// one v_cvt_pk_bf16_f32: packs 2 fp32 -> 2 bf16 in a u32 (RNE)
__device__ __forceinline__ uint32_t cvt_pk_bf16(float lo, float hi) {
    uint32_t r;
    asm("v_cvt_pk_bf16_f32 %0, %1, %2" : "=v"(r) : "v"(lo), "v"(hi));
    return r;
}

// ---------------- stage 1a: fp32 -> bf16, 3 tensors fused ------------------
__global__ void convert3(const float* __restrict__ a, const float* __restrict__ b,
                         const float* __restrict__ c,
                         ushort* __restrict__ oa, ushort* __restrict__ ob,
                         ushort* __restrict__ oc, int n4) {
    const float* in = blockIdx.y == 0 ? a : blockIdx.y == 1 ? b : c;
    ushort* out     = blockIdx.y == 0 ? oa : blockIdx.y == 1 ? ob : oc;
    for (int i = blockIdx.x * blockDim.x + threadIdx.x; i < n4; i += gridDim.x * blockDim.x) {
        float4 v = reinterpret_cast<const float4*>(in)[i];
        ushort4 o;
        o.x = f2bf(v.x); o.y = f2bf(v.y); o.z = f2bf(v.z); o.w = f2bf(v.w);
        reinterpret_cast<ushort4*>(out)[i] = o;
    }
}

// ---------------- stage 1b: W (K=1024,N=1024) fp32 -> WT (N,K) bf16, x4 ----
__global__ void transpose_w4(const float* __restrict__ w0, const float* __restrict__ w1,
                             const float* __restrict__ w2, const float* __restrict__ w3,
                             ushort* __restrict__ o0, ushort* __restrict__ o1,
                             ushort* __restrict__ o2, ushort* __restrict__ o3) {
    const float* in = blockIdx.z == 0 ? w0 : blockIdx.z == 1 ? w1 : blockIdx.z == 2 ? w2 : w3;
    ushort* out     = blockIdx.z == 0 ? o0 : blockIdx.z == 1 ? o1 : blockIdx.z == 2 ? o2 : o3;
    __shared__ float tile[64][65];
    const int tx = threadIdx.x & 63, ty = threadIdx.x >> 6;
    const int nb = blockIdx.x * 64, kb = blockIdx.y * 64;
#pragma unroll
    for (int i = ty; i < 64; i += 4)
        tile[i][tx] = in[(size_t)(kb + i) * 1024 + nb + tx];
    __syncthreads();
#pragma unroll
    for (int i = ty; i < 64; i += 4)
        out[(size_t)(nb + i) * 1024 + kb + tx] = f2bf(tile[tx][i]);
}

// ---------------- GEMM body macro: stage + MFMA main loop ------------------
// Computes acc[4][4] for C-tile (mb,nb) of A(M=8192,K) * BT(N,K)^T.
#define GEMM_BODY(A_, BT_)                                                          \
    f32x4 acc[4][4] = {};                                                           \
    for (int k0 = 0; k0 < 1024; k0 += 32) {                                         \
        _Pragma("unroll")                                                           \
        for (int jj = 0; jj < 2; ++jj) {                                            \
            const int t = jj * 256 + tid;                                           \
            const ushort* ga = A_  + (size_t)(mb + (t >> 2)) * 1024 + k0 + (t & 3) * 8; \
            const ushort* gb = BT_ + (size_t)(nb + (t >> 2)) * 1024 + k0 + (t & 3) * 8; \
            const int lo = (jj * 256 + (tid & ~63)) * 8;                            \
            __builtin_amdgcn_global_load_lds((GLB)ga, (LDS)(As + lo), 16, 0, 0);    \
            __builtin_amdgcn_global_load_lds((GLB)gb, (LDS)(Bs + lo), 16, 0, 0);    \
        }                                                                           \
        __syncthreads();                                                            \
        bf16x8 af[4], bfr[4];                                                       \
        _Pragma("unroll")                                                           \
        for (int i = 0; i < 4; ++i) {                                               \
            af[i]  = *(const bf16x8*)&As[(wr * 64 + i * 16 + r) * 32 + g * 8];      \
            bfr[i] = *(const bf16x8*)&Bs[(wc * 64 + i * 16 + r) * 32 + g * 8];      \
        }                                                                           \
        __builtin_amdgcn_s_setprio(1);                                              \
        _Pragma("unroll")                                                           \
        for (int mi = 0; mi < 4; ++mi)                                              \
            _Pragma("unroll")                                                       \
            for (int ni = 0; ni < 4; ++ni)                                          \
                acc[mi][ni] = __builtin_amdgcn_mfma_f32_16x16x32_bf16(af[mi], bfr[ni], acc[mi][ni], 0, 0, 0); \
        __builtin_amdgcn_s_setprio(0);                                              \
        __syncthreads();                                                            \
    }

// ---------------- stage 2: batched QKV projection GEMM ---------------------
// grid (512, 3): y selects projection (0=Q scaled, 1=K, 2=V transposed out).
// x XCD-swizzled: id = j*8 + xcd; per XCD 8 M-panels x 8 N-blocks.
__global__ __launch_bounds__(256) void gemm_qkv(const ushort* __restrict__ qb,
                                                const ushort* __restrict__ kb,
                                                const ushort* __restrict__ vb,
                                                const ushort* __restrict__ WqT,
                                                const ushort* __restrict__ WkT,
                                                const ushort* __restrict__ WvT,
                                                const float* __restrict__ Wq_b,
                                                const float* __restrict__ Wk_b,
                                                const float* __restrict__ Wv_b,
                                                ushort* __restrict__ Qp,
                                                ushort* __restrict__ Kp,
                                                ushort* __restrict__ Vt,
                                                float qscale) {
    __shared__ ushort As[128 * 32];
    __shared__ ushort Bs[128 * 32];
    const int tid = threadIdx.x;
    const int lane = tid & 63;
    const int wave = tid >> 6, wr = wave >> 1, wc = wave & 1;
    const int r = lane & 15, g = lane >> 4;
    const int proj = blockIdx.y;
    const int id = blockIdx.x;
    const int xcd = id & 7, j = id >> 3;
    const int bx = j >> 3, by = xcd * 8 + (j & 7);
    const int mb = by * 128, nb = bx * 128;

    const ushort* A    = proj == 0 ? qb : proj == 1 ? kb : vb;
    const ushort* BT   = proj == 0 ? WqT : proj == 1 ? WkT : WvT;
    const float*  bias = proj == 0 ? Wq_b : proj == 1 ? Wk_b : Wv_b;

    GEMM_BODY(A, BT)

    const float oscale = proj == 0 ? qscale : 1.0f;
#pragma unroll
    for (int ni = 0; ni < 4; ++ni) {
        const int col = nb + wc * 64 + ni * 16 + r;
        const float bv = bias[col];
#pragma unroll
        for (int mi = 0; mi < 4; ++mi) {
            const int m0 = mb + wr * 64 + mi * 16 + g * 4;
            if (proj < 2) {
                ushort* C = proj == 0 ? Qp : Kp;
#pragma unroll
                for (int i = 0; i < 4; ++i)
                    C[(size_t)(m0 + i) * 1024 + col] = f2bf((acc[mi][ni][i] + bv) * oscale);
            } else {
                const int b = m0 >> 11, s = m0 & 2047;
                const int h = col >> 6, dv = col & 63;
                ushort4 o;
                o.x = f2bf(acc[mi][ni][0] + bv);
                o.y = f2bf(acc[mi][ni][1] + bv);
                o.z = f2bf(acc[mi][ni][2] + bv);
                o.w = f2bf(acc[mi][ni][3] + bv);
                *(ushort4*)&Vt[(((size_t)(b * 16 + h) * 64 + dv) << 11) + s] = o;
            }
        }
    }
}

// ---------------- stage 4: output GEMM + bias -> fp32 ----------------------
__global__ __launch_bounds__(256) void gemm_out(const ushort* __restrict__ A_,
                                                const ushort* __restrict__ BT_,
                                                const float* __restrict__ bias,
                                                float* __restrict__ Cf) {
    __shared__ ushort As[128 * 32];
    __shared__ ushort Bs[128 * 32];
    const int tid = threadIdx.x;
    const int lane = tid & 63;
    const int wave = tid >> 6, wr = wave >> 1, wc = wave & 1;
    const int r = lane & 15, g = lane >> 4;
    const int id = blockIdx.x;
    const int xcd = id & 7, j = id >> 3;
    const int bx = j >> 3, by = xcd * 8 + (j & 7);
    const int mb = by * 128, nb = bx * 128;

    GEMM_BODY(A_, BT_)

#pragma unroll
    for (int ni = 0; ni < 4; ++ni) {
        const int col = nb + wc * 64 + ni * 16 + r;
        const float bv = bias[col];
#pragma unroll
        for (int mi = 0; mi < 4; ++mi) {
            const int m0 = mb + wr * 64 + mi * 16 + g * 4;
#pragma unroll
            for (int i = 0; i < 4; ++i)
                Cf[(size_t)(m0 + i) * 1024 + col] = acc[mi][ni][i] + bv;
        }
    }
}

// ---------------- stage 3: flash attention ---------------------------------
// 1-D grid 512 (XCD-swizzled: 8 q-tiles of a (b,h) share an XCD -> K/V
// L2-resident per XCD). Block 512 thr = 8 waves, 32 q-rows each.
// Softmax: round-5-proven exp2-domain online softmax with defer-max THR=8.
__global__ __launch_bounds__(512, 4) void attn_kernel(const ushort* __restrict__ Qp,
                                                      const ushort* __restrict__ Kp,
                                                      const ushort* __restrict__ Vt,
                                                      ushort* __restrict__ AO) {
    const int tid = threadIdx.x;
    const int lane = tid & 63, wave = tid >> 6;
    const int r = lane & 15, g = lane >> 4;
    // XCD-bijective decomposition (512 = 8 xcd x 8 grp x 8 qt)
    const int id = blockIdx.x;
    const int xcd = id & 7, j = id >> 3;
    const int qt = j & 7;
    const int grp = xcd * 8 + (j >> 3);      // (b,h) group 0..63
    const int h = grp & 15, b = grp >> 4;
    const int qbase = qt * 256 + wave * 32;

    const ushort* Qh = Qp + (size_t)b * 2048 * 1024 + h * 64;
    const ushort* Kh = Kp + (size_t)b * 2048 * 1024 + h * 64;
    const ushort* Vh = Vt + ((size_t)(b * 16 + h)) * 64 * 2048;

    __shared__ ushort Ks[2][64 * 64];   // [buf][row*64 + col], XOR-swizzled
    __shared__ ushort Vs[2][64 * 64];
    __shared__ ushort Pl[8][32 * 64];   // per-wave P tile
    ushort* Pw = (ushort*)Pl[wave];

    // staging geometry: thread tid stages 16B; row = tid>>3, swizzled source col
    const int srow = tid >> 3;                                  // 0..63
    const int scb  = ((tid & 7) * 16) ^ ((srow & 7) << 4);      // swizzled byte col
    const ushort* gKb = Kh + (size_t)srow * 1024 + (scb >> 1);
    const ushort* gVb = Vh + (size_t)srow * 2048 + (scb >> 1);
    const int wlds = wave * 512;                                // wave-uniform elems

    // Q fragments (B-operand of swapped QK): qf[gg][kc]
    bf16x8 qf[2][2];
#pragma unroll
    for (int gg = 0; gg < 2; ++gg)
#pragma unroll
        for (int kc = 0; kc < 2; ++kc)
            qf[gg][kc] = *(const bf16x8*)&Qh[(size_t)(qbase + gg * 16 + r) * 1024 + kc * 32 + g * 8];

    f32x4 oacc[2][4] = {};
    float mrow[2] = {-1e30f, -1e30f};
    float ell[2] = {0.f, 0.f};

    // prologue: stage tile 0 into buf 0
    __builtin_amdgcn_global_load_lds((GLB)gKb, (LDS)(Ks[0] + wlds), 16, 0, 0);
    __builtin_amdgcn_global_load_lds((GLB)gVb, (LDS)(Vs[0] + wlds), 16, 0, 0);
    __syncthreads();

    for (int t0 = 0; t0 < 2048; t0 += 64) {
        const int cur = (t0 >> 6) & 1;
        if (t0 + 64 < 2048) {   // issue next-tile stage; overlaps compute below
            __builtin_amdgcn_global_load_lds((GLB)(gKb + (size_t)(t0 + 64) * 1024),
                                             (LDS)(Ks[cur ^ 1] + wlds), 16, 0, 0);
            __builtin_amdgcn_global_load_lds((GLB)(gVb + (t0 + 64)),
                                             (LDS)(Vs[cur ^ 1] + wlds), 16, 0, 0);
        }

        // K fragments from LDS (swizzled read)
        bf16x8 kf[4][2];
#pragma unroll
        for (int tf = 0; tf < 4; ++tf)
#pragma unroll
            for (int kc = 0; kc < 2; ++kc) {
                const int row = tf * 16 + r;
                const int by = row * 128 + ((kc * 64 + g * 16) ^ ((row & 7) << 4));
                kf[tf][kc] = *(const bf16x8*)((const char*)Ks[cur] + by);
            }

        // St = K * Q^T : st[gg][tf], t = tf*16 + g*4 + i, q = gg*16 + r
        f32x4 st[2][4] = {};
        __builtin_amdgcn_s_setprio(1);
#pragma unroll
        for (int gg = 0; gg < 2; ++gg)
#pragma unroll
            for (int tf = 0; tf < 4; ++tf)
#pragma unroll
                for (int kc = 0; kc < 2; ++kc)
                    st[gg][tf] = __builtin_amdgcn_mfma_f32_16x16x32_bf16(kf[tf][kc], qf[gg][kc], st[gg][tf], 0, 0, 0);
        __builtin_amdgcn_s_setprio(0);

        // ---- online softmax (exp2 domain; Q pre-scaled) ----
        float tmax[2];
#pragma unroll
        for (int gg = 0; gg < 2; ++gg) {
            float m01 = fmaxf(fmaxf(st[gg][0][0], st[gg][0][1]), fmaxf(st[gg][0][2], st[gg][0][3]));
            float m23 = fmaxf(fmaxf(st[gg][1][0], st[gg][1][1]), fmaxf(st[gg][1][2], st[gg][1][3]));
            float m45 = fmaxf(fmaxf(st[gg][2][0], st[gg][2][1]), fmaxf(st[gg][2][2], st[gg][2][3]));
            float m67 = fmaxf(fmaxf(st[gg][3][0], st[gg][3][1]), fmaxf(st[gg][3][2], st[gg][3][3]));
            float t = fmaxf(fmaxf(m01, m23), fmaxf(m45, m67));
            t = fmaxf(t, __shfl_xor(t, 16));
            t = fmaxf(t, __shfl_xor(t, 32));
            tmax[gg] = t;
        }
        // defer-max: skip rescale while growth bounded (P <= 2^8)
        const bool defer = __all((tmax[0] <= mrow[0] + 8.f) & (tmax[1] <= mrow[1] + 8.f));
        if (!defer) {
#pragma unroll
            for (int gg = 0; gg < 2; ++gg) {
                const float mnew = fmaxf(mrow[gg], tmax[gg]);
                const float corr = __builtin_amdgcn_exp2f(mrow[gg] - mnew);
                ell[gg] *= corr;
#pragma unroll
                for (int mf = 0; mf < 4; ++mf)
#pragma unroll
                    for (int i = 0; i < 4; ++i) oacc[gg][mf][i] *= corr;
                mrow[gg] = mnew;
            }
        }
#pragma unroll
        for (int gg = 0; gg < 2; ++gg) {
            const int row = gg * 16 + r;
            float psum = 0.f;
#pragma unroll
            for (int tf = 0; tf < 4; ++tf) {
                const float p0 = __builtin_amdgcn_exp2f(st[gg][tf][0] - mrow[gg]);
                const float p1 = __builtin_amdgcn_exp2f(st[gg][tf][1] - mrow[gg]);
                const float p2 = __builtin_amdgcn_exp2f(st[gg][tf][2] - mrow[gg]);
                const float p3 = __builtin_amdgcn_exp2f(st[gg][tf][3] - mrow[gg]);
                psum += (p0 + p1) + (p2 + p3);
                uint2 pk;
                pk.x = cvt_pk_bf16(p0, p1);
                pk.y = cvt_pk_bf16(p2, p3);
                const int cb = (tf * 32 + g * 8) ^ ((row & 7) << 4);
                *(uint2*)((char*)Pw + row * 128 + cb) = pk;
            }
            psum += __shfl_xor(psum, 16);
            psum += __shfl_xor(psum, 32);
            ell[gg] += psum;
        }

        // V fragments from LDS (swizzled read)
        bf16x8 vf[4][2];
#pragma unroll
        for (int mf = 0; mf < 4; ++mf)
#pragma unroll
            for (int kc = 0; kc < 2; ++kc) {
                const int row = mf * 16 + r;
                const int by = row * 128 + ((kc * 64 + g * 16) ^ ((row & 7) << 4));
                vf[mf][kc] = *(const bf16x8*)((const char*)Vs[cur] + by);
            }

        // O^T += V^T * P^T
        __builtin_amdgcn_s_setprio(1);
#pragma unroll
        for (int gg = 0; gg < 2; ++gg) {
            const int row = gg * 16 + r;
#pragma unroll
            for (int kc = 0; kc < 2; ++kc) {
                const int cb = (kc * 64 + g * 16) ^ ((row & 7) << 4);
                const bf16x8 pf = *(const bf16x8*)((const char*)Pw + row * 128 + cb);
#pragma unroll
                for (int mf = 0; mf < 4; ++mf)
                    oacc[gg][mf] = __builtin_amdgcn_mfma_f32_16x16x32_bf16(vf[mf][kc], pf, oacc[gg][mf], 0, 0, 0);
            }
        }
        __builtin_amdgcn_s_setprio(0);

        // drain stage (compiler emits vmcnt(0) before s_barrier) + buffer flip
        __syncthreads();
    }

    // epilogue: AO[b][q][h*64+dv] = O^T[dv][q] / ell[q]
#pragma unroll
    for (int gg = 0; gg < 2; ++gg) {
        const float inv = 1.f / ell[gg];
        const int q = qbase + gg * 16 + r;
#pragma unroll
        for (int mf = 0; mf < 4; ++mf) {
            ushort4 o;
            o.x = f2bf(oacc[gg][mf][0] * inv);
            o.y = f2bf(oacc[gg][mf][1] * inv);
            o.z = f2bf(oacc[gg][mf][2] * inv);
            o.w = f2bf(oacc[gg][mf][3] * inv);
            *(ushort4*)&AO[(size_t)(b * 2048 + q) * 1024 + h * 64 + mf * 16 + g * 4] = o;
        }
    }
}

// ---------------------------------------------------------------------------
extern "C" void kernel_launch(void* const* d_in, const int* in_sizes, int n_in,
                              void* d_out, int out_size, void* d_ws, size_t ws_size,
                              hipStream_t stream) {
    const float* q_f  = (const float*)d_in[0];
    const float* k_f  = (const float*)d_in[1];
    const float* v_f  = (const float*)d_in[2];
    const float* Wq_w = (const float*)d_in[3];
    const float* Wq_b = (const float*)d_in[4];
    const float* Wk_w = (const float*)d_in[5];
    const float* Wk_b = (const float*)d_in[6];
    const float* Wv_w = (const float*)d_in[7];
    const float* Wv_b = (const float*)d_in[8];
    const float* Wo_w = (const float*)d_in[9];
    const float* Wo_b = (const float*)d_in[10];
    float* out = (float*)d_out;
    char* ws = (char*)d_ws;

    const size_t MB = 1ull << 20;
    ushort* qb  = (ushort*)(ws);                 // 16 MB
    ushort* kb  = (ushort*)(ws + 16 * MB);       // 16 MB
    ushort* vb  = (ushort*)(ws + 32 * MB);       // 16 MB
    ushort* WqT = (ushort*)(ws + 48 * MB);       // 2 MB
    ushort* WkT = (ushort*)(ws + 50 * MB);       // 2 MB
    ushort* WvT = (ushort*)(ws + 52 * MB);       // 2 MB
    ushort* WoT = (ushort*)(ws + 54 * MB);       // 2 MB
    ushort* Qp  = (ushort*)(ws + 56 * MB);       // 16 MB
    ushort* Kp  = (ushort*)(ws + 72 * MB);       // 16 MB
    ushort* Vt  = (ushort*)(ws + 88 * MB);       // 16 MB  (end: 104 MB)
    ushort* AO  = qb;                            // reuse (qb dead after stage 2)

    const int n4 = (4 * 2048 * 1024) / 4;
    convert3<<<dim3(1024, 3), 256, 0, stream>>>(q_f, k_f, v_f, qb, kb, vb, n4);

    transpose_w4<<<dim3(16, 16, 4), 256, 0, stream>>>(Wq_w, Wk_w, Wv_w, Wo_w,
                                                      WqT, WkT, WvT, WoT);

    // fold attention scale (1/sqrt(2048)) and log2(e) into Q projection
    constexpr float QSCALE = (float)(1.4426950408889634 / 45.254833995939045);

    gemm_qkv<<<dim3(512, 3), 256, 0, stream>>>(qb, kb, vb, WqT, WkT, WvT,
                                               Wq_b, Wk_b, Wv_b, Qp, Kp, Vt, QSCALE);

    attn_kernel<<<512, 512, 0, stream>>>(Qp, Kp, Vt, AO);

    gemm_out<<<512, 256, 0, stream>>>(AO, WoT, Wo_b, out);
}